// Round 7
// baseline (1563.135 us; speedup 1.0000x reference)
//
#include <hip/hip_runtime.h>
#include <math.h>

#define BB 512
#define SS 16
#define HH 501
#define CC 7
#define CH 128                 // k chunks of 4
#define PBK (4*BB)             // floats per packed chunk = 2048
#define OFF_ENC (BB*SS*SS)

#define BUFSZ (136*PBK)        // 128 chunks + 8 cushion (depth-8 prefetch)
#define O_BUFIN 0
#define O_BUFH  BUFSZ
#define O_ALIST (2*BUFSZ)
#define O_ELIST (O_ALIST + SS*BB)
#define O_CLS   (O_ELIST + SS*BB)

__device__ __forceinline__ float4 ld4(const float* p) { return *(const float4*)p; }
__device__ __forceinline__ float sigm(float x) { return 1.f / (1.f + expf(-x)); }

__device__ __forceinline__ int PACK(int k, int b) {
    return (k >> 2) * PBK + b * 4 + (k & 3);
}

// swizzled decode: bidx%8 == rg%8 so all 8 col-blocks of one row-group land
// on one XCD (weight slice fetched into a single L2). 1024-block grid,
// 16 no-op blocks (rg 126,127).
__device__ __forceinline__ bool decode(int bidx, int& rg, int& ch) {
    rg = (bidx & 7) | ((bidx >> 6) << 3);
    ch = (bidx >> 3) & 7;
    return rg < 126;
}

// ---------------- prep: z -> packed zT (bufH), cls, zero dep region ---------
__global__ __launch_bounds__(256) void k_prep(
    const float* __restrict__ z, const float* __restrict__ xenc,
    float* __restrict__ bufH, int* __restrict__ cls, float* __restrict__ out)
{
    const int b = blockIdx.x, tid = threadIdx.x;
    if (b < 256) {
        __shared__ float t[32][33];
        const int bt = b >> 4, kt = b & 15;
        const int b0 = bt * 32, k0 = kt * 32;
        const int tx = tid & 31, ty = tid >> 5;
#pragma unroll
        for (int i = 0; i < 4; ++i) {
            int row = ty + i * 8;
            t[row][tx] = (k0 + tx < HH) ? z[(b0 + row) * HH + k0 + tx] : 0.f;
        }
        __syncthreads();
#pragma unroll
        for (int i = 0; i < 4; ++i) {
            int row = ty + i * 8;
            int k = k0 + row;
            float v = (k < HH) ? t[tx][row] : 0.f;
            bufH[PACK(k, b0 + tx)] = v;
        }
    } else if (b < 264) {
        int base = (b - 256) * 1024 + tid * 4;
#pragma unroll
        for (int q = 0; q < 4; ++q) {
            int e = base + q; int s = e >> 9, bb = e & 511;
            const float* xp = xenc + (bb * SS + s) * CC;
            int c = 0;
#pragma unroll
            for (int cc = 0; cc < CC; ++cc) if (xp[cc] > 0.5f) c = cc;
            cls[s * BB + bb] = c;
        }
    } else {
        float4 z4 = make_float4(0.f, 0.f, 0.f, 0.f);
        float4* o4 = (float4*)out;
#pragma unroll
        for (int q = 0; q < 4; ++q)
            o4[(b - 264) * 1024 + q * 256 + tid] = z4;
    }
}

// ---------------- g0 = (z @ Wlin1^T + b)^T packed : bufH -> bufIn -----------
__global__ __launch_bounds__(256, 4) void k_g0(
    const float* __restrict__ act, const float* __restrict__ W,
    const float* __restrict__ blin1, float* __restrict__ dst)
{
    int rg, ch;
    if (!decode(blockIdx.x, rg, ch)) return;
    __shared__ float wl[4][512];
    const int tid = threadIdx.x, lane = tid & 63;
    const int wv = __builtin_amdgcn_readfirstlane(tid >> 6);
    const int r = rg * 4 + wv;
#pragma unroll
    for (int j = 0; j < 4; ++j) {
        int rr = rg * 4 + j;
        const float* src = W + (size_t)min(rr, HH - 1) * HH;
        bool ok = rr < HH;
        for (int k = tid; k < 512; k += 256)
            wl[j][k] = (ok && k < HH) ? src[k] : 0.f;
    }
    __syncthreads();
    const int c = ch * 64 + lane;
    const float* ap = act + c * 4;
    float4 A[8];
#pragma unroll
    for (int q = 0; q < 8; ++q) A[q] = ld4(ap + q * PBK);
    float4 Wr[2];
    Wr[0] = ld4(&wl[wv][0]);
    float acc = 0.f;
    for (int t = 0; t < 16; ++t) {
#pragma unroll
        for (int u = 0; u < 8; ++u) {
            const int kc = t * 8 + u;
            float4 x = A[u];
            A[u] = ld4(ap + (kc + 8) * PBK);
            float4 w = Wr[kc & 1];
            int kw = (kc + 1 < CH) ? kc + 1 : CH - 1;
            Wr[(kc + 1) & 1] = ld4(&wl[wv][kw * 4]);
            acc = fmaf(w.x, x.x, acc); acc = fmaf(w.y, x.y, acc);
            acc = fmaf(w.z, x.z, acc); acc = fmaf(w.w, x.w, acc);
        }
    }
    if (r < HH) dst[PACK(r, c)] = acc + blin1[r];
}

// ---------------- GRU: bufIn(hin, packed) -> bufH(h, packed) ----------------
__global__ __launch_bounds__(256, 4) void k_gru(
    const float* __restrict__ act, const float* __restrict__ Whh,
    const int* __restrict__ cls,
    const float* __restrict__ bhh, const float* __restrict__ Wih,
    const float* __restrict__ bih, int idx, float* __restrict__ dst)
{
    int rg, ch;
    if (!decode(blockIdx.x, rg, ch)) return;
    __shared__ float wl[12][512];
    const int tid = threadIdx.x, lane = tid & 63;
    const int wv = __builtin_amdgcn_readfirstlane(tid >> 6);
    const int r = rg * 4 + wv;
#pragma unroll
    for (int j = 0; j < 12; ++j) {
        int g = j >> 2, rl = j & 3, rr = rg * 4 + rl;
        const float* src = Whh + (size_t)(g * HH + min(rr, HH - 1)) * HH;
        bool ok = rr < HH;
        for (int k = tid; k < 512; k += 256)
            wl[j][k] = (ok && k < HH) ? src[k] : 0.f;
    }
    const int c = ch * 64 + lane;
    const int cc = cls[idx * BB + c];
    const float hp = act[PACK(min(r, HH - 1), c)];
    __syncthreads();
    const float* ap = act + c * 4;
    float4 A[8];
#pragma unroll
    for (int q = 0; q < 8; ++q) A[q] = ld4(ap + q * PBK);
    float4 W0[2], W1[2], W2[2];
    W0[0] = ld4(&wl[0 * 4 + wv][0]);
    W1[0] = ld4(&wl[1 * 4 + wv][0]);
    W2[0] = ld4(&wl[2 * 4 + wv][0]);
    float a0 = 0.f, a1 = 0.f, a2 = 0.f;
    for (int t = 0; t < 16; ++t) {
#pragma unroll
        for (int u = 0; u < 8; ++u) {
            const int kc = t * 8 + u;
            float4 x = A[u];
            A[u] = ld4(ap + (kc + 8) * PBK);
            float4 w0 = W0[kc & 1], w1 = W1[kc & 1], w2 = W2[kc & 1];
            int kw = (kc + 1 < CH) ? kc + 1 : CH - 1;
            W0[(kc + 1) & 1] = ld4(&wl[0 * 4 + wv][kw * 4]);
            W1[(kc + 1) & 1] = ld4(&wl[1 * 4 + wv][kw * 4]);
            W2[(kc + 1) & 1] = ld4(&wl[2 * 4 + wv][kw * 4]);
            a0 = fmaf(w0.x, x.x, a0); a0 = fmaf(w0.y, x.y, a0);
            a0 = fmaf(w0.z, x.z, a0); a0 = fmaf(w0.w, x.w, a0);
            a1 = fmaf(w1.x, x.x, a1); a1 = fmaf(w1.y, x.y, a1);
            a1 = fmaf(w1.z, x.z, a1); a1 = fmaf(w1.w, x.w, a1);
            a2 = fmaf(w2.x, x.x, a2); a2 = fmaf(w2.y, x.y, a2);
            a2 = fmaf(w2.z, x.z, a2); a2 = fmaf(w2.w, x.w, a2);
        }
    }
    if (r < HH) {
        float gi0 = Wih[(0 * HH + r) * CC + cc] + bih[r];
        float gi1 = Wih[(1 * HH + r) * CC + cc] + bih[HH + r];
        float gi2 = Wih[(2 * HH + r) * CC + cc] + bih[2 * HH + r];
        float rgt = sigm(gi0 + a0 + bhh[r]);
        float ugt = sigm(gi1 + a1 + bhh[HH + r]);
        float ngt = tanhf(gi2 + rgt * (a2 + bhh[2 * HH + r]));
        dst[PACK(r, c)] = (1.f - ugt) * ngt + ugt * hp;
    }
}

// ---------------- post: bufH(h) -> bufIn(next hin) + dots/outputs -----------
__global__ __launch_bounds__(256, 4) void k_post(
    const float* __restrict__ actH, const float* __restrict__ actIn,
    const float* __restrict__ Wgate, const float* __restrict__ bgate,
    const float* __restrict__ Wmap,  const float* __restrict__ bmap,
    const float* __restrict__ dep,
    const float* __restrict__ Wedge, const float* __restrict__ bedge,
    const float* __restrict__ Wvert, const float* __restrict__ bvert,
    int idx, int ngemm, int dsrc,
    float* __restrict__ dst, float* __restrict__ Alist,
    float* __restrict__ Elist, float* __restrict__ out)
{
    __shared__ float wl[9][512];
    const int tid = threadIdx.x, lane = tid & 63;
    const int wv = __builtin_amdgcn_readfirstlane(tid >> 6);
    if ((int)blockIdx.x < ngemm) {
        int rg, ch;
        if (!decode(blockIdx.x, rg, ch)) return;
        const int r = rg * 4 + wv;
#pragma unroll
        for (int j = 0; j < 8; ++j) {
            int t2 = j >> 2, rl = j & 3, rr = rg * 4 + rl;
            const float* src = (t2 ? Wmap : Wgate) + (size_t)min(rr, HH - 1) * HH;
            bool ok = rr < HH;
            for (int k = tid; k < 512; k += 256)
                wl[j][k] = (ok && k < HH) ? src[k] : 0.f;
        }
        const int c = ch * 64 + lane;
        const float d = dep[c * (SS * SS) + (idx + 1) * SS + idx];
        __syncthreads();
        const float* ap = actH + c * 4;
        float4 A[8];
#pragma unroll
        for (int q = 0; q < 8; ++q) A[q] = ld4(ap + q * PBK);
        float4 W0[2], W1[2];
        W0[0] = ld4(&wl[0 * 4 + wv][0]);
        W1[0] = ld4(&wl[1 * 4 + wv][0]);
        float a0 = 0.f, a1 = 0.f;
        for (int t = 0; t < 16; ++t) {
#pragma unroll
            for (int u = 0; u < 8; ++u) {
                const int kc = t * 8 + u;
                float4 x = A[u];
                A[u] = ld4(ap + (kc + 8) * PBK);
                float4 w0 = W0[kc & 1], w1 = W1[kc & 1];
                int kw = (kc + 1 < CH) ? kc + 1 : CH - 1;
                W0[(kc + 1) & 1] = ld4(&wl[0 * 4 + wv][kw * 4]);
                W1[(kc + 1) & 1] = ld4(&wl[1 * 4 + wv][kw * 4]);
                a0 = fmaf(w0.x, x.x, a0); a0 = fmaf(w0.y, x.y, a0);
                a0 = fmaf(w0.z, x.z, a0); a0 = fmaf(w0.w, x.w, a0);
                a1 = fmaf(w1.x, x.x, a1); a1 = fmaf(w1.y, x.y, a1);
                a1 = fmaf(w1.z, x.z, a1); a1 = fmaf(w1.w, x.w, a1);
            }
        }
        if (r < HH) {
            float bgv = bgate[r], bmv = bmap[r];
            float c0v = sigm(bgv) * bmv;
            float f = sigm(a0 + bgv) * (a1 + bmv);
            dst[PACK(r, c)] = (d != 0.f) ? (f + 15.f * c0v) : (16.f * c0v);
        }
    } else {
        // dot role: 2 blocks x 256 threads = 512 batch entries
#pragma unroll
        for (int j = 0; j < 9; ++j) {
            const float* src = (j < 2) ? (Wedge + j * HH) : (Wvert + (j - 2) * HH);
            for (int k = tid; k < 512; k += 256)
                wl[j][k] = (k < HH) ? src[k] : 0.f;
        }
        __syncthreads();
        const int db = ((int)blockIdx.x - ngemm) * 256 + tid;
        const float* hp = (dsrc ? actH : actIn) + db * 4;
        float4 A[8];
#pragma unroll
        for (int q = 0; q < 8; ++q) A[q] = ld4(hp + q * PBK);
        float p[9];
#pragma unroll
        for (int j = 0; j < 9; ++j) p[j] = 0.f;
        for (int t = 0; t < 16; ++t) {
#pragma unroll
            for (int u = 0; u < 8; ++u) {
                const int kc = t * 8 + u;
                float4 x = A[u];
                A[u] = ld4(hp + (kc + 8) * PBK);
#pragma unroll
                for (int j = 0; j < 9; ++j) {
                    float4 w = ld4(&wl[j][kc * 4]);
                    p[j] = fmaf(w.x, x.x, p[j]); p[j] = fmaf(w.y, x.y, p[j]);
                    p[j] = fmaf(w.z, x.z, p[j]); p[j] = fmaf(w.w, x.w, p[j]);
                }
            }
        }
        if (idx >= 0) { Alist[idx * BB + db] = p[0]; Elist[idx * BB + db] = p[1]; }
        if (idx <= SS - 2) {
            float lv[CC]; float mx = -1e30f;
#pragma unroll
            for (int c = 0; c < CC; ++c) { lv[c] = p[2 + c] + bvert[c]; mx = fmaxf(mx, lv[c]); }
            float sum = 0.f; float ev[CC];
#pragma unroll
            for (int c = 0; c < CC; ++c) { ev[c] = expf(lv[c] - mx); sum += ev[c]; }
            float inv = 1.f / sum;
#pragma unroll
            for (int c = 0; c < CC; ++c)
                out[OFF_ENC + (db * SS + (idx + 1)) * CC + c] = ev[c] * inv;
        }
        if (idx >= 1) {
            float be = bedge[0];
            float aprev = Alist[(idx - 1) * BB + db], eprev = Elist[(idx - 1) * BB + db];
            out[db * SS * SS + idx * SS + (idx - 1)] =
                (aprev + eprev + be >= 0.f) ? 1.f : 0.f;
            for (int vj = 0; vj <= idx - 2; ++vj)
                out[db * SS * SS + idx * SS + vj] =
                    (p[0] + Elist[vj * BB + db] + be >= 0.f) ? 1.f : 0.f;
        }
    }
}

extern "C" void kernel_launch(void* const* d_in, const int* in_sizes, int n_in,
                              void* d_out, int out_size, void* d_ws, size_t ws_size,
                              hipStream_t stream)
{
    const float* z     = (const float*)d_in[0];
    const float* dep   = (const float*)d_in[1];
    const float* xenc  = (const float*)d_in[2];
    const float* Wlin1 = (const float*)d_in[3];
    const float* blin1 = (const float*)d_in[4];
    const float* Wvert = (const float*)d_in[5];
    const float* bvert = (const float*)d_in[6];
    const float* Wedge = (const float*)d_in[7];
    const float* bedge = (const float*)d_in[8];
    const float* Wgate = (const float*)d_in[9];
    const float* bgate = (const float*)d_in[10];
    const float* Wmap  = (const float*)d_in[11];
    const float* bmap  = (const float*)d_in[12];
    const float* Wih   = (const float*)d_in[13];
    const float* bih   = (const float*)d_in[14];
    const float* Whh   = (const float*)d_in[15];
    const float* bhh   = (const float*)d_in[16];
    float* out = (float*)d_out;

    float* ws    = (float*)d_ws;
    float* bufIn = ws + O_BUFIN;
    float* bufH  = ws + O_BUFH;
    float* Alist = ws + O_ALIST;
    float* Elist = ws + O_ELIST;
    int*   cls   = (int*)(ws + O_CLS);

    k_prep<<<296, 256, 0, stream>>>(z, xenc, bufH, cls, out);
    k_g0<<<1024, 256, 0, stream>>>(bufH, Wlin1, blin1, bufIn);
    // enc row 0 from g0 (dots only, src = bufIn)
    k_post<<<2, 256, 0, stream>>>(bufH, bufIn, Wgate, bgate, Wmap, bmap, dep,
                                  Wedge, bedge, Wvert, bvert, -1, 0, 0,
                                  bufIn, Alist, Elist, out);
    for (int idx = 0; idx < SS; ++idx) {
        k_gru<<<1024, 256, 0, stream>>>(bufIn, Whh, cls, bhh, Wih, bih, idx, bufH);
        int ng = (idx < SS - 1) ? 1024 : 0;
        k_post<<<ng + 2, 256, 0, stream>>>(bufH, bufIn, Wgate, bgate, Wmap, bmap,
                                           dep, Wedge, bedge, Wvert, bvert,
                                           idx, ng, 1,
                                           bufIn, Alist, Elist, out);
    }
}

// Round 8
// 1457.116 us; speedup vs baseline: 1.0728x; 1.0728x over previous
//
#include <hip/hip_runtime.h>
#include <math.h>

#define BB 512
#define SS 16
#define HH 501
#define KK 512
#define CC 7
#define OFF_ENC (BB*SS*SS)

// ws layout (float offsets)
#define O_BUFIN 0
#define O_BUFH  (O_BUFIN + KK*BB)          // 262144
#define O_WHH   (O_BUFH + KK*BB)           // [512][2048] interleaved rp*4+g
#define O_WPM   (O_WHH + KK*2048)          // [512][1024] interleaved rp*2+t
#define O_WLIN  (O_WPM + KK*1024)          // [512][512]
#define O_ALIST (O_WLIN + KK*512)
#define O_ELIST (O_ALIST + SS*BB)
#define O_CLS   (O_ELIST + SS*BB)

__device__ __forceinline__ float4 ld4(const float* p) { return *(const float4*)p; }
__device__ __forceinline__ float sigm(float x) { return 1.f / (1.f + expf(-x)); }

// ---------------- prep: zT, weight transposes, cls, zero regions ------------
__global__ __launch_bounds__(256) void k_prep(
    const float* __restrict__ z, const float* __restrict__ xenc,
    const float* __restrict__ Wlin1, const float* __restrict__ Wgate,
    const float* __restrict__ Wmap,  const float* __restrict__ Whh,
    float* __restrict__ ws, float* __restrict__ out)
{
    __shared__ float ls[32][513];
    const int b = blockIdx.x, tid = threadIdx.x;
    float* bufIn = ws + O_BUFIN;
    float* bufH  = ws + O_BUFH;
    if (b < 256) {
        // transpose z[512][501] -> bufH[k][512] (k-pad rows -> 0)
        __shared__ float t[32][33];
        const int bt = b >> 4, kt = b & 15;
        const int b0 = bt * 32, k0 = kt * 32;
        const int tx = tid & 31, ty = tid >> 5;
#pragma unroll
        for (int i = 0; i < 4; ++i) {
            int row = ty + i * 8;
            t[row][tx] = (k0 + tx < HH) ? z[(b0 + row) * HH + k0 + tx] : 0.f;
        }
        __syncthreads();
#pragma unroll
        for (int i = 0; i < 4; ++i) {
            int row = ty + i * 8;
            int k = k0 + row;
            bufH[(size_t)k * BB + b0 + tx] = (k < HH) ? t[tx][row] : 0.f;
        }
    } else if (b == 256) {
        // zero k-pad rows of bufIn (bufH pads handled above)
        for (int q = tid; q < (KK - HH) * BB; q += 256) bufIn[HH * BB + q] = 0.f;
    } else if (b < 265) {
        int* cls = (int*)(ws + O_CLS);
        int base = (b - 257) * 1024 + tid * 4;
#pragma unroll
        for (int q = 0; q < 4; ++q) {
            int e = base + q; int s = e >> 9, bb = e & 511;
            const float* xp = xenc + (bb * SS + s) * CC;
            int c = 0;
#pragma unroll
            for (int cc = 0; cc < CC; ++cc) if (xp[cc] > 0.5f) c = cc;
            cls[s * BB + bb] = c;
        }
    } else if (b < 297) {
        float4 z4 = make_float4(0.f, 0.f, 0.f, 0.f);
        float4* o4 = (float4*)out;
#pragma unroll
        for (int q = 0; q < 4; ++q)
            o4[(b - 265) * 1024 + q * 256 + tid] = z4;
    } else {
        // weight transposes to k-major interleaved layouts
        int bid2 = b - 297;
        const float* src; float* dst; int WN, M, off, rp0;
        if (bid2 < 48) {
            int g = bid2 >> 4; rp0 = (bid2 & 15) * 32;
            src = Whh + (size_t)g * HH * HH;
            dst = ws + O_WHH; WN = 2048; M = 4; off = g;
        } else if (bid2 < 80) {
            int t2 = (bid2 - 48) >> 4; rp0 = ((bid2 - 48) & 15) * 32;
            src = (t2 ? Wmap : Wgate); dst = ws + O_WPM; WN = 1024; M = 2; off = t2;
        } else {
            rp0 = (bid2 - 80) * 32;
            src = Wlin1; dst = ws + O_WLIN; WN = 512; M = 1; off = 0;
        }
        for (int i = tid; i < 32 * 512; i += 256) {
            int rr = i >> 9, k = i & 511;
            int rp = rp0 + rr;
            ls[rr][k] = (rp < HH && k < HH) ? src[(size_t)rp * HH + k] : 0.f;
        }
        __syncthreads();
        for (int pass = 0; pass < 64; ++pass) {
            int k = pass * 8 + (tid >> 5), rp = tid & 31;
            dst[(size_t)k * WN + (size_t)(rp0 + rp) * M + off] = ls[rp][k];
        }
    }
}

// ---------------- double-buffered tiled GEMM core ---------------------------
// C-tile: 64 weight-cols (r0..r0+63) x 32 batch (b0..b0+31); thread: 4x2.
__device__ __forceinline__ void gemm_tile(
    const float* __restrict__ actG, const float* __restrict__ wtG, int NS,
    int b0, int r0, int tid, float* atile, float* wtile, float acc[4][2])
{
    const int colg = tid & 15, rowg = tid >> 4;
    const int ak = tid >> 3, ab = (tid & 7) * 4;
    const int wk = tid >> 4, wr = (tid & 15) * 4;
    const float* agp = actG + (size_t)ak * BB + b0 + ab;
    const float* wgp = wtG + (size_t)wk * NS + r0 + wr;
    float4 ar0 = ld4(agp), ar1 = ld4(agp + 32 * BB);
    float4 wr0 = ld4(wgp), wr1 = ld4(wgp + 16 * NS);
    float4 wr2 = ld4(wgp + 32 * NS), wr3 = ld4(wgp + 48 * NS);
    int p = 0;
    for (int c = 0; c < 8; ++c) {
        float* at = atile + p * 2048;
        float* wt = wtile + p * 4096;
        *(float4*)&at[ak * 32 + ab] = ar0;
        *(float4*)&at[(ak + 32) * 32 + ab] = ar1;
        *(float4*)&wt[wk * 64 + wr] = wr0;
        *(float4*)&wt[(wk + 16) * 64 + wr] = wr1;
        *(float4*)&wt[(wk + 32) * 64 + wr] = wr2;
        *(float4*)&wt[(wk + 48) * 64 + wr] = wr3;
        __syncthreads();
        if (c < 7) {
            const float* ag = agp + (size_t)(c + 1) * 64 * BB;
            const float* wg = wgp + (size_t)(c + 1) * 64 * NS;
            ar0 = ld4(ag); ar1 = ld4(ag + 32 * BB);
            wr0 = ld4(wg); wr1 = ld4(wg + 16 * NS);
            wr2 = ld4(wg + 32 * NS); wr3 = ld4(wg + 48 * NS);
        }
        const float* ab2 = at + colg * 2;
        const float* wb2 = wt + rowg * 4;
#pragma unroll 8
        for (int k = 0; k < 64; ++k) {
            const float2 a = *(const float2*)&ab2[k * 32];
            const float4 w = *(const float4*)&wb2[k * 64];
            acc[0][0] = fmaf(w.x, a.x, acc[0][0]); acc[0][1] = fmaf(w.x, a.y, acc[0][1]);
            acc[1][0] = fmaf(w.y, a.x, acc[1][0]); acc[1][1] = fmaf(w.y, a.y, acc[1][1]);
            acc[2][0] = fmaf(w.z, a.x, acc[2][0]); acc[2][1] = fmaf(w.z, a.y, acc[2][1]);
            acc[3][0] = fmaf(w.w, a.x, acc[3][0]); acc[3][1] = fmaf(w.w, a.y, acc[3][1]);
        }
        __syncthreads();
        p ^= 1;
    }
}

// ---------------- g0: bufH(zT) @ WT_lin -> bufIn ----------------------------
__global__ __launch_bounds__(256, 2) void k_g0(
    const float* __restrict__ act, const float* __restrict__ WT,
    const float* __restrict__ blin1, float* __restrict__ dst)
{
    __shared__ float atile[2 * 2048];
    __shared__ float wtile[2 * 4096];
    const int tid = threadIdx.x;
    const int ct = blockIdx.x & 15, rt = blockIdx.x >> 4;   // rt 0..7
    const int b0 = ct * 32, r0 = rt * 64;
    float acc[4][2] = {};
    gemm_tile(act, WT, 512, b0, r0, tid, atile, wtile, acc);
    const int colg = tid & 15, rowg = tid >> 4;
    const int c0 = b0 + colg * 2;
#pragma unroll
    for (int j = 0; j < 4; ++j) {
        int r = r0 + rowg * 4 + j;
        if (r < HH) {
            float bv = blin1[r];
            dst[(size_t)r * BB + c0] = acc[j][0] + bv;
            dst[(size_t)r * BB + c0 + 1] = acc[j][1] + bv;
        }
    }
}

// ---------------- GRU: bufIn @ WT_hh (gate-interleaved) -> bufH -------------
__global__ __launch_bounds__(256, 2) void k_gru(
    const float* __restrict__ act, const float* __restrict__ WT,
    const int* __restrict__ cls,
    const float* __restrict__ bhh, const float* __restrict__ Wih,
    const float* __restrict__ bih, int idx, float* __restrict__ dst)
{
    __shared__ float atile[2 * 2048];
    __shared__ float wtile[2 * 4096];
    const int tid = threadIdx.x;
    const int ct = blockIdx.x & 15, rt = blockIdx.x >> 4;   // rt 0..31
    const int b0 = ct * 32, r0 = rt * 64;
    float acc[4][2] = {};
    gemm_tile(act, WT, 2048, b0, r0, tid, atile, wtile, acc);
    const int colg = tid & 15, rowg = tid >> 4;
    const int rp = rt * 16 + rowg;
    if (rp < HH) {
        const int c0 = b0 + colg * 2;
        float bh0 = bhh[rp], bh1 = bhh[HH + rp], bh2 = bhh[2 * HH + rp];
        float bi0 = bih[rp], bi1 = bih[HH + rp], bi2 = bih[2 * HH + rp];
#pragma unroll
        for (int cb = 0; cb < 2; ++cb) {
            int c = c0 + cb;
            int cc = cls[idx * BB + c];
            float gi0 = Wih[(0 * HH + rp) * CC + cc] + bi0;
            float gi1 = Wih[(1 * HH + rp) * CC + cc] + bi1;
            float gi2 = Wih[(2 * HH + rp) * CC + cc] + bi2;
            float rgt = sigm(gi0 + acc[0][cb] + bh0);
            float ugt = sigm(gi1 + acc[1][cb] + bh1);
            float ngt = tanhf(gi2 + rgt * (acc[2][cb] + bh2));
            float hp = act[(size_t)rp * BB + c];
            dst[(size_t)rp * BB + c] = (1.f - ugt) * ngt + ugt * hp;
        }
    }
}

// ---------------- post: bufH @ WT_pm -> bufIn, + dots/outputs ---------------
__global__ __launch_bounds__(256, 2) void k_post(
    const float* __restrict__ actH, const float* __restrict__ actIn,
    const float* __restrict__ WT,
    const float* __restrict__ bgate, const float* __restrict__ bmap,
    const float* __restrict__ dep,
    const float* __restrict__ Wedge, const float* __restrict__ bedge,
    const float* __restrict__ Wvert, const float* __restrict__ bvert,
    int idx, int ngemm, int dsrc,
    float* __restrict__ dst, float* __restrict__ Alist,
    float* __restrict__ Elist, float* __restrict__ out)
{
    __shared__ float atile[2 * 2048];
    __shared__ float wtile[2 * 4096];
    const int tid = threadIdx.x;
    if ((int)blockIdx.x < ngemm) {
        const int ct = blockIdx.x & 15, rt = blockIdx.x >> 4;   // rt 0..15
        const int b0 = ct * 32, r0 = rt * 64;
        float acc[4][2] = {};
        gemm_tile(actH, WT, 1024, b0, r0, tid, atile, wtile, acc);
        const int colg = tid & 15, rowg = tid >> 4;
        const int c0 = b0 + colg * 2;
        float d[2];
#pragma unroll
        for (int cb = 0; cb < 2; ++cb)
            d[cb] = dep[(size_t)(c0 + cb) * (SS * SS) + (idx + 1) * SS + idx];
#pragma unroll
        for (int u = 0; u < 2; ++u) {
            int rp = rt * 32 + rowg * 2 + u;
            if (rp < HH) {
                float bgv = bgate[rp], bmv = bmap[rp];
                float c0v = sigm(bgv) * bmv;
#pragma unroll
                for (int cb = 0; cb < 2; ++cb) {
                    float f = sigm(acc[u * 2 + 0][cb] + bgv) * (acc[u * 2 + 1][cb] + bmv);
                    dst[(size_t)rp * BB + c0 + cb] =
                        (d[cb] != 0.f) ? (f + 15.f * c0v) : (16.f * c0v);
                }
            }
        }
    } else {
        // dot role: 2 blocks x 256 threads = 512 batch entries
        float* wl = wtile;  // 9*512 <= 8192
#pragma unroll
        for (int j = 0; j < 9; ++j) {
            const float* src = (j < 2) ? (Wedge + j * HH) : (Wvert + (j - 2) * HH);
            for (int k = tid; k < 512; k += 256)
                wl[j * 512 + k] = (k < HH) ? src[k] : 0.f;
        }
        __syncthreads();
        const int db = ((int)blockIdx.x - ngemm) * 256 + tid;
        const float* hp = (dsrc ? actH : actIn) + db;
        float p[9];
#pragma unroll
        for (int j = 0; j < 9; ++j) p[j] = 0.f;
#pragma unroll 4
        for (int k = 0; k < 512; ++k) {
            float av = hp[(size_t)k * BB];
#pragma unroll
            for (int j = 0; j < 9; ++j) p[j] = fmaf(wl[j * 512 + k], av, p[j]);
        }
        if (idx >= 0) { Alist[idx * BB + db] = p[0]; Elist[idx * BB + db] = p[1]; }
        if (idx <= SS - 2) {
            float lv[CC]; float mx = -1e30f;
#pragma unroll
            for (int c = 0; c < CC; ++c) { lv[c] = p[2 + c] + bvert[c]; mx = fmaxf(mx, lv[c]); }
            float sum = 0.f; float ev[CC];
#pragma unroll
            for (int c = 0; c < CC; ++c) { ev[c] = expf(lv[c] - mx); sum += ev[c]; }
            float inv = 1.f / sum;
#pragma unroll
            for (int c = 0; c < CC; ++c)
                out[OFF_ENC + (db * SS + (idx + 1)) * CC + c] = ev[c] * inv;
        }
        if (idx >= 1) {
            float be = bedge[0];
            float aprev = Alist[(idx - 1) * BB + db], eprev = Elist[(idx - 1) * BB + db];
            out[db * SS * SS + idx * SS + (idx - 1)] =
                (aprev + eprev + be >= 0.f) ? 1.f : 0.f;
            for (int vj = 0; vj <= idx - 2; ++vj)
                out[db * SS * SS + idx * SS + vj] =
                    (p[0] + Elist[vj * BB + db] + be >= 0.f) ? 1.f : 0.f;
        }
    }
}

extern "C" void kernel_launch(void* const* d_in, const int* in_sizes, int n_in,
                              void* d_out, int out_size, void* d_ws, size_t ws_size,
                              hipStream_t stream)
{
    const float* z     = (const float*)d_in[0];
    const float* dep   = (const float*)d_in[1];
    const float* xenc  = (const float*)d_in[2];
    const float* Wlin1 = (const float*)d_in[3];
    const float* blin1 = (const float*)d_in[4];
    const float* Wvert = (const float*)d_in[5];
    const float* bvert = (const float*)d_in[6];
    const float* Wedge = (const float*)d_in[7];
    const float* bedge = (const float*)d_in[8];
    const float* Wgate = (const float*)d_in[9];
    const float* bgate = (const float*)d_in[10];
    const float* Wmap  = (const float*)d_in[11];
    const float* bmap  = (const float*)d_in[12];
    const float* Wih   = (const float*)d_in[13];
    const float* bih   = (const float*)d_in[14];
    const float* Whh   = (const float*)d_in[15];
    const float* bhh   = (const float*)d_in[16];
    float* out = (float*)d_out;

    float* ws    = (float*)d_ws;
    float* bufIn = ws + O_BUFIN;
    float* bufH  = ws + O_BUFH;
    float* WThh  = ws + O_WHH;
    float* WTpm  = ws + O_WPM;
    float* WTlin = ws + O_WLIN;
    float* Alist = ws + O_ALIST;
    float* Elist = ws + O_ELIST;
    int*   cls   = (int*)(ws + O_CLS);

    k_prep<<<393, 256, 0, stream>>>(z, xenc, Wlin1, Wgate, Wmap, Whh, ws, out);
    k_g0<<<128, 256, 0, stream>>>(bufH, WTlin, blin1, bufIn);
    // enc row 0 from g0 (dots only, src = bufIn)
    k_post<<<2, 256, 0, stream>>>(bufH, bufIn, WTpm, bgate, bmap, dep,
                                  Wedge, bedge, Wvert, bvert, -1, 0, 0,
                                  bufIn, Alist, Elist, out);
    for (int idx = 0; idx < SS; ++idx) {
        k_gru<<<512, 256, 0, stream>>>(bufIn, WThh, cls, bhh, Wih, bih, idx, bufH);
        int ng = (idx < SS - 1) ? 256 : 0;
        k_post<<<ng + 2, 256, 0, stream>>>(bufH, bufIn, WTpm, bgate, bmap,
                                           dep, Wedge, bedge, Wvert, bvert,
                                           idx, ng, 1,
                                           bufIn, Alist, Elist, out);
    }
}